// Round 5
// baseline (419.090 us; speedup 1.0000x reference)
//
#include <hip/hip_runtime.h>
#include <math.h>

// Problem constants (fixed by setup_inputs)
#define B_  32
#define N_  1024
#define D_  64
#define H_  8
#define K_  128
#define HK_ 1024

// ---------------------------------------------------------------------------
// K1: x[b,n,d] = mean_t node_set[b,d,n,t]; inv_xn[b,n] = 1/||x[b,n,:]||;
// part1[(b*16+tile)*64+d] = sum_{n in tile} x[b,n,d]   (pure stores, no atomics)
// ---------------------------------------------------------------------------
__global__ __launch_bounds__(512) void k1_mean(const float* __restrict__ ns,
        float* __restrict__ x, float* __restrict__ invxn,
        float* __restrict__ part1) {
    __shared__ float tile[64][65];
    int b    = blockIdx.x >> 4;
    int n0   = (blockIdx.x & 15) << 6;
    int lane = threadIdx.x & 63;
    int w    = threadIdx.x >> 6;            // 0..7
    #pragma unroll
    for (int j = 0; j < 8; ++j) {
        int d = w * 8 + j;
        const float4* p = (const float4*)(ns +
            ((size_t)((b * 64 + d) * 1024 + n0 + lane)) * 12);   // 48B aligned
        float4 a = p[0], c = p[1], e = p[2];
        float s = ((a.x + a.y) + (a.z + a.w)) + ((c.x + c.y) + (c.z + c.w))
                + ((e.x + e.y) + (e.z + e.w));
        tile[lane][d] = s * (1.0f / 12.0f);
    }
    __syncthreads();
    #pragma unroll
    for (int j = 0; j < 8; ++j) {
        int r = w * 8 + j;
        float v = tile[r][lane];
        x[((size_t)(b * 1024 + n0 + r)) * 64 + lane] = v;
        float ss = v * v;
        #pragma unroll
        for (int o = 32; o; o >>= 1) ss += __shfl_xor(ss, o);
        if (lane == 0) invxn[b * 1024 + n0 + r] = 1.0f / sqrtf(fmaxf(ss, 1e-30f));
    }
    if (threadIdx.x < 64) {
        float s = 0.0f;
        #pragma unroll 16
        for (int r = 0; r < 64; ++r) s += tile[r][threadIdx.x];
        part1[(size_t)blockIdx.x * 64 + threadIdx.x] = s;   // blockIdx = b*16+tile
    }
}

// ---------------------------------------------------------------------------
// K3: deterministic. Per block (b, 256-n slice): reduce part1 (fixed order) ->
// temp, h_avg = tanh(temp@W0), att[n] = x.h_avg, cent partial for slice ->
// part2[(b*4+slice)*64+d]. grid = B*4, block 256.
// ---------------------------------------------------------------------------
__global__ __launch_bounds__(256) void k3_cent(const float* __restrict__ x,
        const float* __restrict__ part1, const float* __restrict__ W0,
        float* __restrict__ part2) {
    __shared__ float t[64];
    __shared__ float ha[64];
    __shared__ float cp[4][64];
    int b    = blockIdx.x >> 2;
    int n0   = (blockIdx.x & 3) << 8;
    int lane = threadIdx.x & 63;
    int w    = threadIdx.x >> 6;
    if (threadIdx.x < 64) {
        float s = 0.0f;
        #pragma unroll
        for (int j = 0; j < 16; ++j) s += part1[(size_t)(b * 16 + j) * 64 + threadIdx.x];
        t[threadIdx.x] = s * (1.0f / 1024.0f);
    }
    __syncthreads();
    if (threadIdx.x < 64) {                  // h_avg: 64x64 matvec
        float a = 0.0f;
        #pragma unroll 8
        for (int d = 0; d < 64; ++d) a += t[d] * W0[d * 64 + threadIdx.x];
        ha[threadIdx.x] = tanhf(a);
    }
    __syncthreads();
    float hv = ha[lane];
    float cw = 0.0f;
    for (int nn = w; nn < 256; nn += 4) {    // fixed per-wave order
        float xv = x[((size_t)(b * 1024 + n0 + nn)) * 64 + lane];
        float d  = xv * hv;
        #pragma unroll
        for (int o = 32; o; o >>= 1) d += __shfl_xor(d, o);   // att broadcast
        cw += d * xv;
    }
    cp[w][lane] = cw;
    __syncthreads();
    if (w == 0)
        part2[(size_t)blockIdx.x * 64 + lane] =
            ((cp[0][lane] + cp[1][lane]) + (cp[2][lane] + cp[3][lane]));
}

// ---------------------------------------------------------------------------
// K4: reconstruct cent from 4 slice partials (fixed order), then centroid MLP
// -> bc, invcn. One wave per 4 hk. grid = 2048, block 256.
// ---------------------------------------------------------------------------
__global__ __launch_bounds__(256) void k4_bc(const float* __restrict__ part2,
        const float* __restrict__ w_i2c, const float* __restrict__ b_i2c,
        const float* __restrict__ W_lin, const float* __restrict__ b_lin,
        float* __restrict__ bc, float* __restrict__ invcn) {
    int lane = threadIdx.x & 63;
    int w    = threadIdx.x >> 6;
    int gg   = blockIdx.x * 4 + w;
    int b    = gg >> 8;
    int kk0  = (gg & 255) * 4;
    float c = 0.0f;
    #pragma unroll
    for (int s = 0; s < 4; ++s) c += part2[(size_t)(b * 4 + s) * 64 + lane];
    float b1[8];
    #pragma unroll
    for (int h = 0; h < 8; ++h) b1[h] = fmaxf(c * w_i2c[h] + b_i2c[h], 0.0f);
    #pragma unroll
    for (int u = 0; u < 4; ++u) {
        int kk = kk0 + u;
        float pre = b_lin[kk];
        #pragma unroll
        for (int h = 0; h < 8; ++h) pre += b1[h] * W_lin[kk * 8 + h];
        float v = fmaxf(pre, 0.0f);
        bc[((size_t)(b * 1024 + kk)) * 64 + lane] = v;
        float ss = v * v;
        #pragma unroll
        for (int o = 32; o; o >>= 1) ss += __shfl_xor(ss, o);
        if (lane == 0) invcn[b * 1024 + kk] = (ss > 0.0f) ? (1.0f / sqrtf(ss)) : 0.0f;
    }
}

// ---------------------------------------------------------------------------
// K5 (dominant, fp32 VALU GEMM): per (b, 64-n tile), loop h over 8 heads.
// Register-prefetch double-buffer of bc staging, 2 barriers/head, per-thread
// normalizer (fixed order). grid = B*16 = 512, block 256, 2 blocks/CU.
// ---------------------------------------------------------------------------
__global__ __launch_bounds__(256, 2) void k5_assign(const float* __restrict__ x,
        const float* __restrict__ bc, const float* __restrict__ invxn,
        const float* __restrict__ invcn, const float* __restrict__ conv_w,
        const float* __restrict__ conv_b, float* __restrict__ C) {
    __shared__ float xt[64][68];     // [n][d] padded
    __shared__ float bct[128][68];   // [k][d]
    __shared__ float invx_s[64];
    __shared__ float invc_s[128];
    __shared__ float sred[16][68];   // [q][n] k-partial sums
    int b   = blockIdx.x >> 4;
    int n0  = (blockIdx.x & 15) << 6;
    int tid = threadIdx.x;
    {   // stage x tile: 64 rows x 64 d
        int r = tid >> 2, dh = (tid & 3) << 4;
        const float4* src = (const float4*)(x + ((size_t)(b * 1024 + n0 + r)) * 64 + dh);
        float4* dst = (float4*)(&xt[r][dh]);
        dst[0] = src[0]; dst[1] = src[1]; dst[2] = src[2]; dst[3] = src[3];
    }
    if (tid < 64) invx_s[tid] = invxn[b * 1024 + n0 + tid];
    {   // prologue: stage head-0 bc tile
        int r = tid >> 1, dh = (tid & 1) << 5;
        const float4* src = (const float4*)(bc + ((size_t)(b * 1024 + r)) * 64 + dh);
        float4* dst = (float4*)(&bct[r][dh]);
        #pragma unroll
        for (int u = 0; u < 8; ++u) dst[u] = src[u];
    }
    if (tid < 128) invc_s[tid] = invcn[b * 1024 + tid];
    float Cacc[8][4];
    #pragma unroll
    for (int i = 0; i < 8; ++i)
        #pragma unroll
        for (int j = 0; j < 4; ++j) Cacc[i][j] = 0.0f;
    int q = tid >> 4, p = tid & 15;          // k-slot (16), n-slot (16)
    float cb = conv_b[0];
    int rr = tid >> 1, dhh = (tid & 1) << 5; // staging coords (reused)
    for (int h = 0; h < 8; ++h) {
        __syncthreads();                     // A: bct[h]/invc_s[h] visible
        // issue prefetch of head h+1 (wraps harmlessly at h=7)
        int hn = (h + 1) & 7;
        float4 pf[8];
        float  pfc = 0.0f;
        {
            const float4* src = (const float4*)(bc + ((size_t)(b * 1024 + hn * 128 + rr)) * 64 + dhh);
            #pragma unroll
            for (int u = 0; u < 8; ++u) pf[u] = src[u];
        }
        if (tid < 128) pfc = invcn[b * 1024 + hn * 128 + tid];
        // GEMM: acc[i][j] = bc_row(q+16i) . x_row(p+16j)
        float acc[8][4];
        #pragma unroll
        for (int i = 0; i < 8; ++i)
            #pragma unroll
            for (int j = 0; j < 4; ++j) acc[i][j] = 0.0f;
        for (int dc = 0; dc < 64; dc += 4) {
            float4 bv[8], xv[4];
            #pragma unroll
            for (int i = 0; i < 8; ++i) bv[i] = *(const float4*)(&bct[q + 16 * i][dc]);
            #pragma unroll
            for (int j = 0; j < 4; ++j) xv[j] = *(const float4*)(&xt[p + 16 * j][dc]);
            #pragma unroll
            for (int i = 0; i < 8; ++i)
                #pragma unroll
                for (int j = 0; j < 4; ++j)
                    acc[i][j] += bv[i].x * xv[j].x + bv[i].y * xv[j].y
                               + bv[i].z * xv[j].z + bv[i].w * xv[j].w;
        }
        // fold cosine denominators; per-thread k-partials of the normalizer
        float part[4];
        #pragma unroll
        for (int j = 0; j < 4; ++j) part[j] = 0.0f;
        #pragma unroll
        for (int i = 0; i < 8; ++i) {
            float ic = invc_s[q + 16 * i];
            #pragma unroll
            for (int j = 0; j < 4; ++j) {
                float v = acc[i][j] * ic * invx_s[p + 16 * j];
                acc[i][j] = v;
                part[j] += v;
            }
        }
        #pragma unroll
        for (int j = 0; j < 4; ++j) sred[q][p + 16 * j] = part[j];
        __syncthreads();                     // B: sred done, GEMM reads done
        {   // commit prefetched head h+1 to LDS (safe: all GEMM reads done)
            float4* dst = (float4*)(&bct[rr][dhh]);
            #pragma unroll
            for (int u = 0; u < 8; ++u) dst[u] = pf[u];
        }
        if (tid < 128) invc_s[tid] = pfc;
        // per-thread normalizer (fixed qq order -> deterministic)
        float cwv = conv_w[h];
        #pragma unroll
        for (int j = 0; j < 4; ++j) {
            float s = 0.0f;
            #pragma unroll
            for (int qq = 0; qq < 16; ++qq) s += sred[qq][p + 16 * j];
            float si = 1.0f / (s + 1e-10f);
            #pragma unroll
            for (int i = 0; i < 8; ++i) Cacc[i][j] += cwv * acc[i][j] * si;
        }
    }
    #pragma unroll
    for (int i = 0; i < 8; ++i) {
        int k = q + 16 * i;
        #pragma unroll
        for (int j = 0; j < 4; ++j)
            C[((size_t)(b * 128 + k)) * 1024 + n0 + p + 16 * j] = Cacc[i][j] + cb;
    }
}

// ---------------------------------------------------------------------------
// K6: LDS-tiled GEMM nns[k,d] = sum_n C[b,k,n]*x[b,n,d], fused projection.
// ---------------------------------------------------------------------------
__global__ __launch_bounds__(256, 2) void k6_out(const float* __restrict__ C,
        const float* __restrict__ x, const float* __restrict__ Wf,
        const float* __restrict__ bfeat, float* __restrict__ out) {
    __shared__ float xt[128][68];
    __shared__ float ct[16][132];
    __shared__ float nnst[16][68];
    __shared__ float wfs[64][68];
    int b   = blockIdx.x >> 3;
    int k0  = (blockIdx.x & 7) << 4;
    int tid = threadIdx.x;
    int kq  = tid >> 4, p = tid & 15;
    for (int t = tid; t < 4096; t += 256) wfs[t >> 6][t & 63] = Wf[t];
    float acc[4] = {0.0f, 0.0f, 0.0f, 0.0f};
    for (int c = 0; c < 8; ++c) {
        __syncthreads();
        {
            int r = tid >> 1, dh = (tid & 1) << 5;
            const float4* src = (const float4*)(x + ((size_t)(b * 1024 + c * 128 + r)) * 64 + dh);
            float4* dst = (float4*)(&xt[r][dh]);
            #pragma unroll
            for (int u = 0; u < 8; ++u) dst[u] = src[u];
        }
        for (int t = tid; t < 2048; t += 256)
            ct[t >> 7][t & 127] = C[((size_t)(b * 128 + k0 + (t >> 7))) * 1024 + c * 128 + (t & 127)];
        __syncthreads();
        #pragma unroll 8
        for (int n = 0; n < 128; ++n) {
            float  cv = ct[kq][n];
            float4 xv = *(const float4*)(&xt[n][p << 2]);
            acc[0] += cv * xv.x; acc[1] += cv * xv.y;
            acc[2] += cv * xv.z; acc[3] += cv * xv.w;
        }
    }
    __syncthreads();
    nnst[kq][(p << 2) + 0] = acc[0];
    nnst[kq][(p << 2) + 1] = acc[1];
    nnst[kq][(p << 2) + 2] = acc[2];
    nnst[kq][(p << 2) + 3] = acc[3];
    __syncthreads();
    float o0 = bfeat[(p << 2) + 0], o1 = bfeat[(p << 2) + 1];
    float o2 = bfeat[(p << 2) + 2], o3 = bfeat[(p << 2) + 3];
    #pragma unroll
    for (int dc = 0; dc < 64; dc += 4) {
        float4 nv = *(const float4*)(&nnst[kq][dc]);
        float4 w0 = *(const float4*)(&wfs[(p << 2) + 0][dc]);
        float4 w1 = *(const float4*)(&wfs[(p << 2) + 1][dc]);
        float4 w2 = *(const float4*)(&wfs[(p << 2) + 2][dc]);
        float4 w3 = *(const float4*)(&wfs[(p << 2) + 3][dc]);
        o0 += nv.x * w0.x + nv.y * w0.y + nv.z * w0.z + nv.w * w0.w;
        o1 += nv.x * w1.x + nv.y * w1.y + nv.z * w1.z + nv.w * w1.w;
        o2 += nv.x * w2.x + nv.y * w2.y + nv.z * w2.z + nv.w * w2.w;
        o3 += nv.x * w3.x + nv.y * w3.y + nv.z * w3.z + nv.w * w3.w;
    }
    float4 ov = make_float4(o0, o1, o2, o3);
    *(float4*)(out + ((size_t)(b * 128 + k0 + kq)) * 64 + (p << 2)) = ov;
}

// ---------------------------------------------------------------------------
extern "C" void kernel_launch(void* const* d_in, const int* in_sizes, int n_in,
                              void* d_out, int out_size, void* d_ws, size_t ws_size,
                              hipStream_t stream) {
    const float* node_set = (const float*)d_in[0];
    // d_in[1] = adj : UNUSED by the reference
    const float* W0     = (const float*)d_in[2];
    const float* w_i2c  = (const float*)d_in[3];
    const float* b_i2c  = (const float*)d_in[4];
    const float* W_lin  = (const float*)d_in[5];
    const float* b_lin  = (const float*)d_in[6];
    const float* conv_w = (const float*)d_in[7];
    const float* conv_b = (const float*)d_in[8];
    const float* W_feat = (const float*)d_in[9];
    const float* b_feat = (const float*)d_in[10];
    float* out = (float*)d_out;
    float* ws  = (float*)d_ws;

    // workspace layout (floats) — every array fully overwritten each call
    float* x     = ws;                      // 2,097,152  [B,N,D]
    float* invxn = ws + 2097152;            //    32,768  [B,N]
    float* part1 = ws + 2129920;            //    32,768  [B,16,64]
    float* part2 = ws + 2162688;            //     8,192  [B,4,64]
    float* bc    = ws + 2170880;            // 2,097,152  [B,HK,D]
    float* invcn = ws + 4268032;            //    32,768  [B,HK]
    float* Cmat  = ws + 4300800;            // 4,194,304  [B,K,N]

    k1_mean  <<<B_ * 16, 512, 0, stream>>>(node_set, x, invxn, part1);
    k3_cent  <<<B_ * 4,  256, 0, stream>>>(x, part1, W0, part2);
    k4_bc    <<<2048,    256, 0, stream>>>(part2, w_i2c, b_i2c, W_lin, b_lin, bc, invcn);
    k5_assign<<<B_ * 16, 256, 0, stream>>>(x, bc, invxn, invcn, conv_w, conv_b, Cmat);
    k6_out   <<<B_ * 8,  256, 0, stream>>>(Cmat, x, W_feat, b_feat, out);
}

// Round 7
// 395.964 us; speedup vs baseline: 1.0584x; 1.0584x over previous
//
#include <hip/hip_runtime.h>
#include <math.h>

// Problem constants (fixed by setup_inputs)
#define B_  32
#define N_  1024
#define D_  64
#define H_  8
#define K_  128
#define HK_ 1024

#define GLB(p) ((const __attribute__((address_space(1))) void*)(p))
#define LDSP(p) ((__attribute__((address_space(3))) void*)(p))

// ---------------------------------------------------------------------------
// K1: x[b,n,d] = mean_t node_set[b,d,n,t]; inv_xn[b,n] = 1/||x[b,n,:]||;
// part1[(b*16+tile)*64+d] = sum_{n in tile} x[b,n,d]  (pure stores, no atomics)
// ---------------------------------------------------------------------------
__global__ __launch_bounds__(512) void k1_mean(const float* __restrict__ ns,
        float* __restrict__ x, float* __restrict__ invxn,
        float* __restrict__ part1) {
    __shared__ float tile[64][65];
    int b    = blockIdx.x >> 4;
    int n0   = (blockIdx.x & 15) << 6;
    int lane = threadIdx.x & 63;
    int w    = threadIdx.x >> 6;            // 0..7
    #pragma unroll
    for (int j = 0; j < 8; ++j) {
        int d = w * 8 + j;
        const float4* p = (const float4*)(ns +
            ((size_t)((b * 64 + d) * 1024 + n0 + lane)) * 12);   // 48B aligned
        float4 a = p[0], c = p[1], e = p[2];
        float s = ((a.x + a.y) + (a.z + a.w)) + ((c.x + c.y) + (c.z + c.w))
                + ((e.x + e.y) + (e.z + e.w));
        tile[lane][d] = s * (1.0f / 12.0f);
    }
    __syncthreads();
    #pragma unroll
    for (int j = 0; j < 8; ++j) {
        int r = w * 8 + j;
        float v = tile[r][lane];
        x[((size_t)(b * 1024 + n0 + r)) * 64 + lane] = v;
        float ss = v * v;
        #pragma unroll
        for (int o = 32; o; o >>= 1) ss += __shfl_xor(ss, o);
        if (lane == 0) invxn[b * 1024 + n0 + r] = 1.0f / sqrtf(fmaxf(ss, 1e-30f));
    }
    if (threadIdx.x < 64) {
        float s = 0.0f;
        #pragma unroll 16
        for (int r = 0; r < 64; ++r) s += tile[r][threadIdx.x];
        part1[(size_t)blockIdx.x * 64 + threadIdx.x] = s;   // blockIdx = b*16+tile
    }
}

// ---------------------------------------------------------------------------
// K3: deterministic. Per block (b, 128-n slice): reduce part1 (fixed order) ->
// temp, h_avg = tanh(temp@W0), att[n] = x.h_avg, cent partial for slice ->
// part2[(b*8+slice)*64+d]. grid = B*8 = 256 blocks (full GPU), block 256.
// ---------------------------------------------------------------------------
__global__ __launch_bounds__(256) void k3_cent(const float* __restrict__ x,
        const float* __restrict__ part1, const float* __restrict__ W0,
        float* __restrict__ part2) {
    __shared__ float t[64];
    __shared__ float ha[64];
    __shared__ float cp[4][64];
    int b    = blockIdx.x >> 3;
    int n0   = (blockIdx.x & 7) << 7;
    int lane = threadIdx.x & 63;
    int w    = threadIdx.x >> 6;
    if (threadIdx.x < 64) {
        float s = 0.0f;
        #pragma unroll
        for (int j = 0; j < 16; ++j) s += part1[(size_t)(b * 16 + j) * 64 + threadIdx.x];
        t[threadIdx.x] = s * (1.0f / 1024.0f);
    }
    __syncthreads();
    if (threadIdx.x < 64) {                  // h_avg: 64x64 matvec
        float a = 0.0f;
        #pragma unroll 8
        for (int d = 0; d < 64; ++d) a += t[d] * W0[d * 64 + threadIdx.x];
        ha[threadIdx.x] = tanhf(a);
    }
    __syncthreads();
    float hv = ha[lane];
    float cw = 0.0f;
    for (int nn = w; nn < 128; nn += 4) {    // fixed per-wave order
        float xv = x[((size_t)(b * 1024 + n0 + nn)) * 64 + lane];
        float d  = xv * hv;
        #pragma unroll
        for (int o = 32; o; o >>= 1) d += __shfl_xor(d, o);   // att broadcast
        cw += d * xv;
    }
    cp[w][lane] = cw;
    __syncthreads();
    if (w == 0)
        part2[(size_t)blockIdx.x * 64 + lane] =
            ((cp[0][lane] + cp[1][lane]) + (cp[2][lane] + cp[3][lane]));
}

// ---------------------------------------------------------------------------
// K4: reconstruct cent from 8 slice partials (fixed order), then centroid MLP
// -> bc, invcn. One wave per 4 hk. grid = 2048, block 256.
// ---------------------------------------------------------------------------
__global__ __launch_bounds__(256) void k4_bc(const float* __restrict__ part2,
        const float* __restrict__ w_i2c, const float* __restrict__ b_i2c,
        const float* __restrict__ W_lin, const float* __restrict__ b_lin,
        float* __restrict__ bc, float* __restrict__ invcn) {
    int lane = threadIdx.x & 63;
    int w    = threadIdx.x >> 6;
    int gg   = blockIdx.x * 4 + w;
    int b    = gg >> 8;
    int kk0  = (gg & 255) * 4;
    float c = 0.0f;
    #pragma unroll
    for (int s = 0; s < 8; ++s) c += part2[(size_t)(b * 8 + s) * 64 + lane];
    float b1[8];
    #pragma unroll
    for (int h = 0; h < 8; ++h) b1[h] = fmaxf(c * w_i2c[h] + b_i2c[h], 0.0f);
    #pragma unroll
    for (int u = 0; u < 4; ++u) {
        int kk = kk0 + u;
        float pre = b_lin[kk];
        #pragma unroll
        for (int h = 0; h < 8; ++h) pre += b1[h] * W_lin[kk * 8 + h];
        float v = fmaxf(pre, 0.0f);
        bc[((size_t)(b * 1024 + kk)) * 64 + lane] = v;
        float ss = v * v;
        #pragma unroll
        for (int o = 32; o; o >>= 1) ss += __shfl_xor(ss, o);
        if (lane == 0) invcn[b * 1024 + kk] = (ss > 0.0f) ? (1.0f / sqrtf(ss)) : 0.0f;
    }
}

// ---------------------------------------------------------------------------
// K5 (dominant, fp32 VALU GEMM, LDS-pipe-bound): per (b, 128-n tile), loop 8
// heads. 8x8 register tile (min LDS reads/FMA), bct double-buffered via
// global_load_lds (XOR-swizzled source -> conflict-free unpadded reads),
// software-pipelined c-loop with named A/B reg sets (no runtime-indexed
// arrays -> no scratch). grid = B*8 = 256 blocks, block 256, 1 block/CU.
// ---------------------------------------------------------------------------
__global__ __launch_bounds__(256, 1) void k5_assign(const float* __restrict__ x,
        const float* __restrict__ bc, const float* __restrict__ invxn,
        const float* __restrict__ invcn, const float* __restrict__ conv_w,
        const float* __restrict__ conv_b, float* __restrict__ C) {
    __shared__ float xt[128][68];        // padded, staged once      (34.8 KB)
    __shared__ float bct[2][128 * 64];   // unpadded, swizzled, dbuf (64 KB)
    __shared__ float invx_s[128];
    __shared__ float invc_s[2][128];
    __shared__ float sredW[128][4];      // [col][wave] partials     (2 KB)
    int b   = blockIdx.x >> 3;
    int n0  = (blockIdx.x & 7) << 7;
    int tid = threadIdx.x;
    int l   = tid & 63, w = tid >> 6;
    int q   = tid >> 4, p = tid & 15;    // k-slot (16), n-slot (16)
    int rxor = q & 7;                    // read-side swizzle key
    int rl  = l >> 4, cl = l & 15;       // staging lane coords
    {   // stage x tile: 128 rows x 64 d (one-time)
        int r = tid >> 1, dh = (tid & 1) << 5;
        const float4* src = (const float4*)(x + ((size_t)(b * 1024 + n0 + r)) * 64 + dh);
        float4* dst = (float4*)(&xt[r][dh]);
        #pragma unroll
        for (int u = 0; u < 8; ++u) dst[u] = src[u];
    }
    if (tid < 128) {
        invx_s[tid]    = invxn[b * 1024 + n0 + tid];
        invc_s[0][tid] = invcn[b * 1024 + tid];
    }
    {   // async stage head-0 bc tile, swizzled source: slot c holds logical c^(r&7)
        const float* hb = bc + ((size_t)(b * 1024)) * 64;
        #pragma unroll
        for (int t = 0; t < 8; ++t) {
            int chunk = w * 8 + t;
            int r = chunk * 4 + rl;
            const float* src = hb + (size_t)r * 64 + ((cl ^ (r & 7)) << 2);
            __builtin_amdgcn_global_load_lds(GLB(src), LDSP(&bct[0][chunk * 256]), 16, 0, 0);
        }
    }
    float Cacc[8][8];
    #pragma unroll
    for (int i = 0; i < 8; ++i)
        #pragma unroll
        for (int j = 0; j < 8; ++j) Cacc[i][j] = 0.0f;
    float cb = conv_b[0];
    __syncthreads();                      // A(0): barrier drains vmcnt

    for (int h = 0; h < 8; ++h) {
        int cur = h & 1, nxt = cur ^ 1;
        float pfc = 0.0f;
        if (h < 7) {   // issue async stage of next head into other buffer
            const float* hb = bc + ((size_t)(b * 1024 + (h + 1) * 128)) * 64;
            #pragma unroll
            for (int t = 0; t < 8; ++t) {
                int chunk = w * 8 + t;
                int r = chunk * 4 + rl;
                const float* src = hb + (size_t)r * 64 + ((cl ^ (r & 7)) << 2);
                __builtin_amdgcn_global_load_lds(GLB(src), LDSP(&bct[nxt][chunk * 256]), 16, 0, 0);
            }
            if (tid < 128) pfc = invcn[b * 1024 + (h + 1) * 128 + tid];
        }
        // GEMM: acc[i][j] = bc_row(q+16i) . x_row(p+16j), software-pipelined
        const float4* B4 = (const float4*)(&bct[cur][0]);
        float acc[8][8];
        #pragma unroll
        for (int i = 0; i < 8; ++i)
            #pragma unroll
            for (int j = 0; j < 8; ++j) acc[i][j] = 0.0f;
        float4 bvA[8], xvA[8], bvB[8], xvB[8];
        #pragma unroll
        for (int i = 0; i < 8; ++i) bvA[i] = B4[(q + 16 * i) * 16 + (0 ^ rxor)];
        #pragma unroll
        for (int j = 0; j < 8; ++j) xvA[j] = *(const float4*)(&xt[p + 16 * j][0]);
        #pragma unroll 1
        for (int c = 0; c < 16; c += 2) {
            #pragma unroll
            for (int i = 0; i < 8; ++i) bvB[i] = B4[(q + 16 * i) * 16 + ((c + 1) ^ rxor)];
            #pragma unroll
            for (int j = 0; j < 8; ++j) xvB[j] = *(const float4*)(&xt[p + 16 * j][(c + 1) << 2]);
            #pragma unroll
            for (int i = 0; i < 8; ++i)
                #pragma unroll
                for (int j = 0; j < 8; ++j)
                    acc[i][j] += bvA[i].x * xvA[j].x + bvA[i].y * xvA[j].y
                               + bvA[i].z * xvA[j].z + bvA[i].w * xvA[j].w;
            if (c + 2 < 16) {
                #pragma unroll
                for (int i = 0; i < 8; ++i) bvA[i] = B4[(q + 16 * i) * 16 + ((c + 2) ^ rxor)];
                #pragma unroll
                for (int j = 0; j < 8; ++j) xvA[j] = *(const float4*)(&xt[p + 16 * j][(c + 2) << 2]);
            }
            #pragma unroll
            for (int i = 0; i < 8; ++i)
                #pragma unroll
                for (int j = 0; j < 8; ++j)
                    acc[i][j] += bvB[i].x * xvB[j].x + bvB[i].y * xvB[j].y
                               + bvB[i].z * xvB[j].z + bvB[i].w * xvB[j].w;
        }
        // fold cosine denominators; per-thread k-partials of the normalizer
        float part[8];
        #pragma unroll
        for (int j = 0; j < 8; ++j) part[j] = 0.0f;
        #pragma unroll
        for (int i = 0; i < 8; ++i) {
            float ic = invc_s[cur][q + 16 * i];
            #pragma unroll
            for (int j = 0; j < 8; ++j) {
                float v = acc[i][j] * ic * invx_s[p + 16 * j];
                acc[i][j] = v;
                part[j] += v;
            }
        }
        // wave-level reduce over the 4 q'-lane-groups (fixed order)
        #pragma unroll
        for (int j = 0; j < 8; ++j) {
            part[j] += __shfl_xor(part[j], 16);
            part[j] += __shfl_xor(part[j], 32);
        }
        if (l < 16) {
            #pragma unroll
            for (int j = 0; j < 8; ++j) sredW[p + 16 * j][w] = part[j];
        }
        __syncthreads();                  // B: sredW done, bct[cur] reads done
        if (h < 7 && tid < 128) invc_s[nxt][tid] = pfc;
        float cwv = conv_w[h];
        #pragma unroll
        for (int j = 0; j < 8; ++j) {
            float4 sv = *(const float4*)(&sredW[p + 16 * j][0]);
            float s  = (sv.x + sv.y) + (sv.z + sv.w);
            float si = 1.0f / (s + 1e-10f);
            #pragma unroll
            for (int i = 0; i < 8; ++i) Cacc[i][j] += cwv * acc[i][j] * si;
        }
        __syncthreads();                  // A(h+1): drains vmcnt for gll loads
    }
    #pragma unroll
    for (int i = 0; i < 8; ++i) {
        int k = q + 16 * i;
        #pragma unroll
        for (int j = 0; j < 8; ++j)
            C[((size_t)(b * 128 + k)) * 1024 + n0 + p + 16 * j] = Cacc[i][j] + cb;
    }
}

// ---------------------------------------------------------------------------
// K6: LDS-tiled GEMM nns[k,d] = sum_n C[b,k,n]*x[b,n,d], fused projection.
// ---------------------------------------------------------------------------
__global__ __launch_bounds__(256, 2) void k6_out(const float* __restrict__ C,
        const float* __restrict__ x, const float* __restrict__ Wf,
        const float* __restrict__ bfeat, float* __restrict__ out) {
    __shared__ float xt[128][68];
    __shared__ float ct[16][132];
    __shared__ float nnst[16][68];
    __shared__ float wfs[64][68];
    int b   = blockIdx.x >> 3;
    int k0  = (blockIdx.x & 7) << 4;
    int tid = threadIdx.x;
    int kq  = tid >> 4, p = tid & 15;
    for (int t = tid; t < 4096; t += 256) wfs[t >> 6][t & 63] = Wf[t];
    float acc[4] = {0.0f, 0.0f, 0.0f, 0.0f};
    for (int c = 0; c < 8; ++c) {
        __syncthreads();
        {
            int r = tid >> 1, dh = (tid & 1) << 5;
            const float4* src = (const float4*)(x + ((size_t)(b * 1024 + c * 128 + r)) * 64 + dh);
            float4* dst = (float4*)(&xt[r][dh]);
            #pragma unroll
            for (int u = 0; u < 8; ++u) dst[u] = src[u];
        }
        for (int t = tid; t < 2048; t += 256)
            ct[t >> 7][t & 127] = C[((size_t)(b * 128 + k0 + (t >> 7))) * 1024 + c * 128 + (t & 127)];
        __syncthreads();
        #pragma unroll 8
        for (int n = 0; n < 128; ++n) {
            float  cv = ct[kq][n];
            float4 xv = *(const float4*)(&xt[n][p << 2]);
            acc[0] += cv * xv.x; acc[1] += cv * xv.y;
            acc[2] += cv * xv.z; acc[3] += cv * xv.w;
        }
    }
    __syncthreads();
    nnst[kq][(p << 2) + 0] = acc[0];
    nnst[kq][(p << 2) + 1] = acc[1];
    nnst[kq][(p << 2) + 2] = acc[2];
    nnst[kq][(p << 2) + 3] = acc[3];
    __syncthreads();
    float o0 = bfeat[(p << 2) + 0], o1 = bfeat[(p << 2) + 1];
    float o2 = bfeat[(p << 2) + 2], o3 = bfeat[(p << 2) + 3];
    #pragma unroll
    for (int dc = 0; dc < 64; dc += 4) {
        float4 nv = *(const float4*)(&nnst[kq][dc]);
        float4 w0 = *(const float4*)(&wfs[(p << 2) + 0][dc]);
        float4 w1 = *(const float4*)(&wfs[(p << 2) + 1][dc]);
        float4 w2 = *(const float4*)(&wfs[(p << 2) + 2][dc]);
        float4 w3 = *(const float4*)(&wfs[(p << 2) + 3][dc]);
        o0 += nv.x * w0.x + nv.y * w0.y + nv.z * w0.z + nv.w * w0.w;
        o1 += nv.x * w1.x + nv.y * w1.y + nv.z * w1.z + nv.w * w1.w;
        o2 += nv.x * w2.x + nv.y * w2.y + nv.z * w2.z + nv.w * w2.w;
        o3 += nv.x * w3.x + nv.y * w3.y + nv.z * w3.z + nv.w * w3.w;
    }
    float4 ov = make_float4(o0, o1, o2, o3);
    *(float4*)(out + ((size_t)(b * 128 + k0 + kq)) * 64 + (p << 2)) = ov;
}

// ---------------------------------------------------------------------------
extern "C" void kernel_launch(void* const* d_in, const int* in_sizes, int n_in,
                              void* d_out, int out_size, void* d_ws, size_t ws_size,
                              hipStream_t stream) {
    const float* node_set = (const float*)d_in[0];
    // d_in[1] = adj : UNUSED by the reference
    const float* W0     = (const float*)d_in[2];
    const float* w_i2c  = (const float*)d_in[3];
    const float* b_i2c  = (const float*)d_in[4];
    const float* W_lin  = (const float*)d_in[5];
    const float* b_lin  = (const float*)d_in[6];
    const float* conv_w = (const float*)d_in[7];
    const float* conv_b = (const float*)d_in[8];
    const float* W_feat = (const float*)d_in[9];
    const float* b_feat = (const float*)d_in[10];
    float* out = (float*)d_out;
    float* ws  = (float*)d_ws;

    // workspace layout (floats) — every array fully overwritten each call
    float* x     = ws;                      // 2,097,152  [B,N,D]
    float* invxn = ws + 2097152;            //    32,768  [B,N]
    float* part1 = ws + 2129920;            //    32,768  [B,16,64]
    float* bc    = ws + 2162688;            // 2,097,152  [B,HK,D]
    float* invcn = ws + 4259840;            //    32,768  [B,HK]
    float* Cmat  = ws + 4292608;            // 4,194,304  [B,K,N]
    float* part2 = Cmat;                    //    16,384  [B,8,64] (dead before k5)

    k1_mean  <<<B_ * 16, 512, 0, stream>>>(node_set, x, invxn, part1);
    k3_cent  <<<B_ * 8,  256, 0, stream>>>(x, part1, W0, part2);
    k4_bc    <<<2048,    256, 0, stream>>>(part2, w_i2c, b_i2c, W_lin, b_lin, bc, invcn);
    k5_assign<<<B_ * 8,  256, 0, stream>>>(x, bc, invxn, invcn, conv_w, conv_b, Cmat);
    k6_out   <<<B_ * 8,  256, 0, stream>>>(Cmat, x, W_feat, b_feat, out);
}